// Round 3
// baseline (212.564 us; speedup 1.0000x reference)
//
#include <hip/hip_runtime.h>
#include <stdint.h>

typedef unsigned short u16;
typedef short bf16x8 __attribute__((ext_vector_type(8)));
typedef float f32x4 __attribute__((ext_vector_type(4)));

#define S_ 2048
#define HID_ 1024
#define H_ 16
#define D_ 64

#define LOG2E 1.4426950408889634f
#define SCALE_LOG2 0.18033688011112042f   /* 0.125 * log2(e) */
#define MAXC_LOG2 11.541560327111707f     /* 8 * log2(e) */

__device__ __forceinline__ float bf2f(u16 u) {
  uint32_t x = ((uint32_t)u) << 16;
  return __builtin_bit_cast(float, x);
}
__device__ __forceinline__ u16 f2bf(float f) {
  uint32_t x = __builtin_bit_cast(uint32_t, f);
  uint32_t r = (x + 0x7fffu + ((x >> 16) & 1u)) >> 16;
  return (u16)r;
}
__device__ __forceinline__ uint32_t packbf2(float a, float b) {
  return (uint32_t)f2bf(a) | ((uint32_t)f2bf(b) << 16);
}

__device__ __forceinline__ void gl2lds16(const void* g, void* l) {
  __builtin_amdgcn_global_load_lds(
      (const __attribute__((address_space(1))) unsigned int*)g,
      (__attribute__((address_space(3))) unsigned int*)l, 16, 0, 0);
}

// ---------------- all fp32 -> bf16 converts in ONE kernel ----------------
__global__ void convert_all_kernel(const float* __restrict__ X, const float* __restrict__ Wq,
                                   const float* __restrict__ Wk, const float* __restrict__ Wv,
                                   u16* __restrict__ Xb, u16* __restrict__ Wqb,
                                   u16* __restrict__ Wkb, u16* __restrict__ Wvb) {
  int i = blockIdx.x * 256 + threadIdx.x;
  const float* src;
  u16* dst;
  int off;
  if (i < (1 << 20)) {
    src = X; dst = Xb; off = i;
  } else if (i < (1 << 20) + (1 << 18)) {
    src = Wq; dst = Wqb; off = i - (1 << 20);
  } else if (i < (1 << 20) + 2 * (1 << 18)) {
    src = Wk; dst = Wkb; off = i - (1 << 20) - (1 << 18);
  } else {
    src = Wv; dst = Wvb; off = i - (1 << 20) - 2 * (1 << 18);
  }
  float4 v = ((const float4*)src)[off];
  uint2 packed;
  packed.x = packbf2(v.x, v.y);
  packed.y = packbf2(v.z, v.w);
  ((uint2*)dst)[off] = packed;
}

// ---------------- RoPE cos/sin tables (S x 32) ----------------
__global__ void rope_table_kernel(float* __restrict__ cos_t, float* __restrict__ sin_t) {
  int t = blockIdx.x * 256 + threadIdx.x;  // 65536 = 2048*32
  int s = t >> 5, i = t & 31;
  float invf = powf(10000.0f, -(float)i * (1.0f / 32.0f));
  float ang = (float)s * invf;
  cos_t[t] = cosf(ang);
  sin_t[t] = sinf(ang);
}

// ---------------- QKV GEMM with fused RoPE epilogue ----------------
// C = X(4096x1024) * W^T. 128x128 tile, BK=64, 4 waves 2x2.
// z<2 uses SWAPPED mfma operands (A=W) so C regs run along n (=d): packed stores.
// z==2 keeps A=X so C regs run along m (=s): packed V^T stores.
__global__ __launch_bounds__(256) void qkv_gemm_kernel(
    const u16* __restrict__ X, const u16* __restrict__ Wq, const u16* __restrict__ Wk,
    const u16* __restrict__ Wv, const float* __restrict__ cos_t,
    const float* __restrict__ sin_t, u16* __restrict__ Q, u16* __restrict__ K,
    u16* __restrict__ Vt) {
  __shared__ char smem[32768];
  char* As = smem;
  char* Bs = smem + 16384;
  int tid = threadIdx.x;
  int lane = tid & 63, wave = tid >> 6;
  int wm = wave >> 1, wn = wave & 1;
  int quad = lane >> 4, l16 = lane & 15;
  int mbase = blockIdx.y * 128, nbase = blockIdx.x * 128;
  int z = blockIdx.z;
  const u16* W = (z == 0) ? Wq : (z == 1) ? Wk : Wv;

  f32x4 acc[4][4] = {};

  for (int k0 = 0; k0 < HID_; k0 += 64) {
#pragma unroll
    for (int it = 0; it < 4; ++it) {
      int i = it * 256 + tid;
      int r = i >> 3, gs = i & 7, gsrc = gs ^ (r & 7);
      gl2lds16(X + (size_t)(mbase + r) * HID_ + k0 + gsrc * 8, As + i * 16);
    }
#pragma unroll
    for (int it = 0; it < 4; ++it) {
      int i = it * 256 + tid;
      int r = i >> 3, gs = i & 7, gsrc = gs ^ (r & 7);
      gl2lds16(W + (size_t)(nbase + r) * HID_ + k0 + gsrc * 8, Bs + i * 16);
    }
    __syncthreads();
#pragma unroll
    for (int kh = 0; kh < 2; ++kh) {
      bf16x8 afrag[4], bfrag[4];
#pragma unroll
      for (int i4 = 0; i4 < 4; ++i4) {
        int r = wm * 64 + i4 * 16 + l16;
        int L = r * 8 + ((kh * 4 + quad) ^ (r & 7));
        afrag[i4] = *(const bf16x8*)(As + L * 16);
      }
#pragma unroll
      for (int j4 = 0; j4 < 4; ++j4) {
        int r = wn * 64 + j4 * 16 + l16;
        int L = r * 8 + ((kh * 4 + quad) ^ (r & 7));
        bfrag[j4] = *(const bf16x8*)(Bs + L * 16);
      }
      if (z == 2) {
#pragma unroll
        for (int i4 = 0; i4 < 4; ++i4)
#pragma unroll
          for (int j4 = 0; j4 < 4; ++j4)
            acc[i4][j4] = __builtin_amdgcn_mfma_f32_16x16x32_bf16(afrag[i4], bfrag[j4],
                                                                  acc[i4][j4], 0, 0, 0);
      } else {
#pragma unroll
        for (int i4 = 0; i4 < 4; ++i4)
#pragma unroll
          for (int j4 = 0; j4 < 4; ++j4)
            acc[i4][j4] = __builtin_amdgcn_mfma_f32_16x16x32_bf16(bfrag[j4], afrag[i4],
                                                                  acc[i4][j4], 0, 0, 0);
      }
    }
    __syncthreads();
  }

  if (z == 2) {
    // C tile (i4,j4): row = m-off = quad*4+reg, col = n-off = l16.
    // 4 regs = 4 consecutive s -> pack 8B stores into Vt (BH,D,S).
#pragma unroll
    for (int i4 = 0; i4 < 4; ++i4)
#pragma unroll
      for (int j4 = 0; j4 < 4; ++j4) {
        int m = mbase + wm * 64 + i4 * 16 + quad * 4;
        int n = nbase + wn * 64 + j4 * 16 + l16;
        int b = m >> 11, s0 = m & 2047;
        int h = n >> 6, d = n & 63;
        uint2 pk;
        pk.x = packbf2(acc[i4][j4][0], acc[i4][j4][1]);
        pk.y = packbf2(acc[i4][j4][2], acc[i4][j4][3]);
        *(uint2*)(Vt + (((size_t)(b * H_ + h)) * D_ + d) * S_ + s0) = pk;
      }
  } else {
    // SWAPPED: C tile (i4,j4): row = n-off = quad*4+reg, col = m-off = l16.
    // 4 regs = 4 consecutive d. RoPE pair (d, d+32) = (j4, j4+2).
    u16* dst = (z == 0) ? Q : K;
#pragma unroll
    for (int i4 = 0; i4 < 4; ++i4)
#pragma unroll
      for (int j4 = 0; j4 < 2; ++j4) {
        int m = mbase + wm * 64 + i4 * 16 + l16;
        int n1 = nbase + wn * 64 + j4 * 16 + quad * 4;
        int b = m >> 11, s = m & 2047;
        int h = n1 >> 6, d1 = n1 & 63;  // d1 in [0,32), multiple of 4
        float4 c4 = *(const float4*)(cos_t + s * 32 + d1);
        float4 s4 = *(const float4*)(sin_t + s * 32 + d1);
        float y1[4], y2[4];
#pragma unroll
        for (int r = 0; r < 4; ++r) {
          float cr = ((const float*)&c4)[r], sr = ((const float*)&s4)[r];
          float x1 = acc[i4][j4][r], x2 = acc[i4][j4 + 2][r];
          y1[r] = x1 * cr - x2 * sr;
          y2[r] = x2 * cr + x1 * sr;
        }
        size_t base = ((size_t)(b * H_ + h) * S_ + s) * D_;
        uint2 p1, p2;
        p1.x = packbf2(y1[0], y1[1]);
        p1.y = packbf2(y1[2], y1[3]);
        p2.x = packbf2(y2[0], y2[1]);
        p2.y = packbf2(y2[2], y2[3]);
        *(uint2*)(dst + base + d1) = p1;
        *(uint2*)(dst + base + d1 + 32) = p2;
      }
  }
}

// ---------------- Flash attention, fixed-max softmax, S^T orientation ----------------
// grid (32 q-tiles, 32 bh). 4 waves x 16 queries. 64-key tiles, double-buffered K/V.
// S^T = K*Q^T -> C: row=key(quad*4+reg), col=q(l16). P packed to LDS as 8B chunks.
__global__ __launch_bounds__(256) void flash_kernel(
    const u16* __restrict__ Q, const u16* __restrict__ K, const u16* __restrict__ Vt,
    const float* __restrict__ mask, float* __restrict__ out) {
  __shared__ char smem[40960];
  // buf b: K at b*16384, V at b*16384+8192. P at 32768 (2 KB/wave).
  int tid = threadIdx.x, lane = tid & 63, wave = tid >> 6;
  int quad = lane >> 4, l16 = lane & 15;
  int bh = blockIdx.y, b = bh >> 4, h = bh & 15;
  int qbase = blockIdx.x * 64;
  int qw = qbase + wave * 16;
  char* Pw = smem + 32768 + wave * 2048;
  const float* mrow = mask + b * S_;
  const u16* Kbase = K + (size_t)bh * S_ * D_;
  const u16* Vbase = Vt + (size_t)bh * D_ * S_;

  bf16x8 qfrag[2];
  {
    const u16* qp = Q + ((size_t)bh * S_ + qw + l16) * D_ + quad * 8;
    qfrag[0] = *(const bf16x8*)qp;
    qfrag[1] = *(const bf16x8*)(qp + 32);
  }
  f32x4 o[4] = {};
  float l_run = 0.f;

  // stage tile 0 into buffer 0
  {
    char* Ks = smem;
    char* Vs = smem + 8192;
#pragma unroll
    for (int it = 0; it < 2; ++it) {
      int i = it * 256 + tid;
      int r = i >> 3, gs = i & 7, gsrc = gs ^ (r & 7);
      gl2lds16(Kbase + (size_t)r * D_ + gsrc * 8, Ks + i * 16);
      gl2lds16(Vbase + (size_t)r * S_ + gsrc * 8, Vs + i * 16);
    }
  }

  for (int kt = 0; kt < 32; ++kt) {
    int kbase = kt * 64;
    char* Ks = smem + (kt & 1) * 16384;
    char* Vs = Ks + 8192;
    __syncthreads();  // staging of current buffer complete (vmcnt drain)

    if (kt < 31) {  // prefetch next tile into other buffer
      char* Kn = smem + ((kt + 1) & 1) * 16384;
      char* Vn = Kn + 8192;
      int nb = kbase + 64;
#pragma unroll
      for (int it = 0; it < 2; ++it) {
        int i = it * 256 + tid;
        int r = i >> 3, gs = i & 7, gsrc = gs ^ (r & 7);
        gl2lds16(Kbase + (size_t)(nb + r) * D_ + gsrc * 8, Kn + i * 16);
        gl2lds16(Vbase + (size_t)r * S_ + nb + gsrc * 8, Vn + i * 16);
      }
    }

    // mask prefetch (per-key float4, broadcast across l16)
    float4 mv4[4];
#pragma unroll
    for (int jt = 0; jt < 4; ++jt)
      mv4[jt] = *(const float4*)(mrow + kbase + jt * 16 + quad * 4);

    // S^T = K * Q^T : row=key, col=q
    f32x4 sacc[4] = {};
#pragma unroll
    for (int jt = 0; jt < 4; ++jt) {
      int r = jt * 16 + l16;
#pragma unroll
      for (int kh = 0; kh < 2; ++kh) {
        int L = r * 8 + ((kh * 4 + quad) ^ (r & 7));
        bf16x8 kf = *(const bf16x8*)(Ks + L * 16);
        sacc[jt] = __builtin_amdgcn_mfma_f32_16x16x32_bf16(kf, qfrag[kh], sacc[jt], 0, 0, 0);
      }
    }

    // fixed-max softmax; truncate to bf16; l from truncated values; packed P writes
#pragma unroll
    for (int jt = 0; jt < 4; ++jt) {
      uint32_t bt[4];
#pragma unroll
      for (int r = 0; r < 4; ++r) {
        float mvs = fmaf(((const float*)&mv4[jt])[r], LOG2E, -MAXC_LOG2);
        float p = __builtin_amdgcn_exp2f(fmaf(sacc[jt][r], SCALE_LOG2, mvs));
        bt[r] = __builtin_bit_cast(uint32_t, p) & 0xffff0000u;
        l_run += __builtin_bit_cast(float, bt[r]);
      }
      uint2 pk;
      pk.x = (bt[0] >> 16) | bt[1];
      pk.y = (bt[2] >> 16) | bt[3];
      int chunk = (jt * 4 + quad) ^ l16;  // 8B chunks, 16 per row, xor-swizzled
      *(uint2*)(Pw + l16 * 128 + chunk * 8) = pk;
    }

    // O += P V : pfrag A-layout from packed P (2x b64 per kh)
    bf16x8 pfrag[2];
#pragma unroll
    for (int kh = 0; kh < 2; ++kh) {
      int c0 = kh * 8 + quad * 2;
      uint2 lo = *(const uint2*)(Pw + l16 * 128 + ((c0) ^ l16) * 8);
      uint2 hi = *(const uint2*)(Pw + l16 * 128 + ((c0 + 1) ^ l16) * 8);
      union { uint2 u[2]; bf16x8 v; } cvt;
      cvt.u[0] = lo;
      cvt.u[1] = hi;
      pfrag[kh] = cvt.v;
    }
#pragma unroll
    for (int jd = 0; jd < 4; ++jd) {
      int r = jd * 16 + l16;
#pragma unroll
      for (int kh = 0; kh < 2; ++kh) {
        int L = r * 8 + ((kh * 4 + quad) ^ (r & 7));
        bf16x8 vf = *(const bf16x8*)(Vs + L * 16);
        o[jd] = __builtin_amdgcn_mfma_f32_16x16x32_bf16(pfrag[kh], vf, o[jd], 0, 0, 0);
      }
    }
  }

  // l reduction: sum over quads (keys were split across quads)
  float lsum = l_run;
  lsum += __shfl_xor(lsum, 16, 64);
  lsum += __shfl_xor(lsum, 32, 64);
  float inv_l[4];
#pragma unroll
  for (int r = 0; r < 4; ++r) inv_l[r] = 1.0f / __shfl(lsum, quad * 4 + r, 64);
#pragma unroll
  for (int jd = 0; jd < 4; ++jd) {
#pragma unroll
    for (int r = 0; r < 4; ++r) {
      int q = qbase + wave * 16 + quad * 4 + r;
      int d = jd * 16 + l16;
      out[(((size_t)b * S_ + q) * H_ + h) * D_ + d] = o[jd][r] * inv_l[r];
    }
  }
}

extern "C" void kernel_launch(void* const* d_in, const int* in_sizes, int n_in,
                              void* d_out, int out_size, void* d_ws, size_t ws_size,
                              hipStream_t stream) {
  const float* hid = (const float*)d_in[0];
  const float* mask = (const float*)d_in[1];
  const float* Wq = (const float*)d_in[2];
  const float* Wk = (const float*)d_in[3];
  const float* Wv = (const float*)d_in[4];
  float* out = (float*)d_out;
  char* ws = (char*)d_ws;

  u16* Xbf = (u16*)ws;                              // 8 MB
  u16* Wqb = (u16*)(ws + (8u << 20));               // 2 MB
  u16* Wkb = (u16*)(ws + (10u << 20));              // 2 MB
  u16* Wvb = (u16*)(ws + (12u << 20));              // 2 MB
  u16* Qb = (u16*)(ws + (14u << 20));               // 8 MB (BH,S,D)
  u16* Kb = (u16*)(ws + (22u << 20));               // 8 MB (BH,S,D)
  u16* Vtb = (u16*)(ws + (30u << 20));              // 8 MB (BH,D,S)
  float* cos_t = (float*)(ws + (38u << 20));        // 256 KB
  float* sin_t = (float*)(ws + (38u << 20) + (256u << 10));

  convert_all_kernel<<<7168, 256, 0, stream>>>(hid, Wq, Wk, Wv, Xbf, Wqb, Wkb, Wvb);
  rope_table_kernel<<<256, 256, 0, stream>>>(cos_t, sin_t);
  qkv_gemm_kernel<<<dim3(8, 32, 3), 256, 0, stream>>>(Xbf, Wqb, Wkb, Wvb, cos_t, sin_t,
                                                      Qb, Kb, Vtb);
  flash_kernel<<<dim3(32, 32), 256, 0, stream>>>(Qb, Kb, Vtb, mask, out);
}

// Round 4
// 179.370 us; speedup vs baseline: 1.1851x; 1.1851x over previous
//
#include <hip/hip_runtime.h>
#include <stdint.h>

typedef unsigned short u16;
typedef short bf16x8 __attribute__((ext_vector_type(8)));
typedef float f32x4 __attribute__((ext_vector_type(4)));

#define S_ 2048
#define HID_ 1024
#define H_ 16
#define D_ 64

#define LOG2E 1.4426950408889634f
#define SCALE_LOG2 0.18033688011112042f   /* 0.125 * log2(e) */
#define MAXC_LOG2 11.541560327111707f     /* 8 * log2(e) */

__device__ __forceinline__ u16 f2bf(float f) {
  uint32_t x = __builtin_bit_cast(uint32_t, f);
  uint32_t r = (x + 0x7fffu + ((x >> 16) & 1u)) >> 16;
  return (u16)r;
}
__device__ __forceinline__ uint32_t packbf2(float a, float b) {
  return (uint32_t)f2bf(a) | ((uint32_t)f2bf(b) << 16);
}

__device__ __forceinline__ void gl2lds16(const void* g, void* l) {
  __builtin_amdgcn_global_load_lds(
      (const __attribute__((address_space(1))) unsigned int*)g,
      (__attribute__((address_space(3))) unsigned int*)l, 16, 0, 0);
}

// ------------- prep: fp32->bf16 converts + RoPE tables, one kernel -------------
#define NX_ (1 << 20)
#define NW_ (1 << 18)
__global__ void prep_kernel(const float* __restrict__ X, const float* __restrict__ Wq,
                            const float* __restrict__ Wk, const float* __restrict__ Wv,
                            u16* __restrict__ Xb, u16* __restrict__ Wqb,
                            u16* __restrict__ Wkb, u16* __restrict__ Wvb,
                            float* __restrict__ cos_t, float* __restrict__ sin_t) {
  int i = blockIdx.x * 256 + threadIdx.x;
  if (i < NX_ + 3 * NW_) {
    const float* src;
    u16* dst;
    int off;
    if (i < NX_) {
      src = X; dst = Xb; off = i;
    } else if (i < NX_ + NW_) {
      src = Wq; dst = Wqb; off = i - NX_;
    } else if (i < NX_ + 2 * NW_) {
      src = Wk; dst = Wkb; off = i - NX_ - NW_;
    } else {
      src = Wv; dst = Wvb; off = i - NX_ - 2 * NW_;
    }
    float4 v = ((const float4*)src)[off];
    uint2 packed;
    packed.x = packbf2(v.x, v.y);
    packed.y = packbf2(v.z, v.w);
    ((uint2*)dst)[off] = packed;
  } else {
    int t = i - (NX_ + 3 * NW_);  // 65536 = 2048*32
    int s = t >> 5, j = t & 31;
    float invf = powf(10000.0f, -(float)j * (1.0f / 32.0f));
    float ang = (float)s * invf;
    cos_t[t] = cosf(ang);
    sin_t[t] = sinf(ang);
  }
}

// ---------------- QKV GEMM, double-buffered, z merged into grid.x ----------------
// C = X(4096x1024) * W^T. 128x128 tile, BK=64, 4 waves 2x2, 1 barrier/iter.
// grid.x in [0,24): which = x>>3 (0:Q 1:K 2:V), nbase = (x&7)*128.
// which<2: SWAPPED mfma operands (C regs run along d) + fused RoPE.
// which==2: C regs run along s -> packed V^T stores.
__global__ __launch_bounds__(256) void qkv_gemm_kernel(
    const u16* __restrict__ X, const u16* __restrict__ Wq, const u16* __restrict__ Wk,
    const u16* __restrict__ Wv, const float* __restrict__ cos_t,
    const float* __restrict__ sin_t, u16* __restrict__ Q, u16* __restrict__ K,
    u16* __restrict__ Vt) {
  __shared__ char smem[65536];  // As[2] @ 0/16K, Bs[2] @ 32K/48K
  int tid = threadIdx.x;
  int lane = tid & 63, wave = tid >> 6;
  int wm = wave >> 1, wn = wave & 1;
  int quad = lane >> 4, l16 = lane & 15;
  int which = blockIdx.x >> 3;
  int nbase = (blockIdx.x & 7) * 128;
  int mbase = blockIdx.y * 128;
  const u16* W = (which == 0) ? Wq : (which == 1) ? Wk : Wv;

  // stage tile 0 into buffer 0
  {
#pragma unroll
    for (int it = 0; it < 4; ++it) {
      int i = it * 256 + tid;
      int r = i >> 3, gs = i & 7, gsrc = gs ^ (r & 7);
      gl2lds16(X + (size_t)(mbase + r) * HID_ + gsrc * 8, smem + i * 16);
      gl2lds16(W + (size_t)(nbase + r) * HID_ + gsrc * 8, smem + 32768 + i * 16);
    }
  }

  f32x4 acc[4][4] = {};

  for (int kk = 0; kk < 16; ++kk) {
    char* As = smem + (kk & 1) * 16384;
    char* Bs = smem + 32768 + (kk & 1) * 16384;
    __syncthreads();  // staging of current buffer complete

    if (kk < 15) {  // prefetch next tile into other buffer
      int k0n = (kk + 1) * 64;
      char* An = smem + ((kk + 1) & 1) * 16384;
      char* Bn = smem + 32768 + ((kk + 1) & 1) * 16384;
#pragma unroll
      for (int it = 0; it < 4; ++it) {
        int i = it * 256 + tid;
        int r = i >> 3, gs = i & 7, gsrc = gs ^ (r & 7);
        gl2lds16(X + (size_t)(mbase + r) * HID_ + k0n + gsrc * 8, An + i * 16);
        gl2lds16(W + (size_t)(nbase + r) * HID_ + k0n + gsrc * 8, Bn + i * 16);
      }
    }

#pragma unroll
    for (int kh = 0; kh < 2; ++kh) {
      bf16x8 afrag[4], bfrag[4];
#pragma unroll
      for (int i4 = 0; i4 < 4; ++i4) {
        int r = wm * 64 + i4 * 16 + l16;
        int L = r * 8 + ((kh * 4 + quad) ^ (r & 7));
        afrag[i4] = *(const bf16x8*)(As + L * 16);
      }
#pragma unroll
      for (int j4 = 0; j4 < 4; ++j4) {
        int r = wn * 64 + j4 * 16 + l16;
        int L = r * 8 + ((kh * 4 + quad) ^ (r & 7));
        bfrag[j4] = *(const bf16x8*)(Bs + L * 16);
      }
      if (which == 2) {
#pragma unroll
        for (int i4 = 0; i4 < 4; ++i4)
#pragma unroll
          for (int j4 = 0; j4 < 4; ++j4)
            acc[i4][j4] = __builtin_amdgcn_mfma_f32_16x16x32_bf16(afrag[i4], bfrag[j4],
                                                                  acc[i4][j4], 0, 0, 0);
      } else {
#pragma unroll
        for (int i4 = 0; i4 < 4; ++i4)
#pragma unroll
          for (int j4 = 0; j4 < 4; ++j4)
            acc[i4][j4] = __builtin_amdgcn_mfma_f32_16x16x32_bf16(bfrag[j4], afrag[i4],
                                                                  acc[i4][j4], 0, 0, 0);
      }
    }
  }

  if (which == 2) {
    // C tile: row = m-off = quad*4+reg, col = n-off = l16. 4 regs = 4 consecutive s.
#pragma unroll
    for (int i4 = 0; i4 < 4; ++i4)
#pragma unroll
      for (int j4 = 0; j4 < 4; ++j4) {
        int m = mbase + wm * 64 + i4 * 16 + quad * 4;
        int n = nbase + wn * 64 + j4 * 16 + l16;
        int b = m >> 11, s0 = m & 2047;
        int h = n >> 6, d = n & 63;
        uint2 pk;
        pk.x = packbf2(acc[i4][j4][0], acc[i4][j4][1]);
        pk.y = packbf2(acc[i4][j4][2], acc[i4][j4][3]);
        *(uint2*)(Vt + (((size_t)(b * H_ + h)) * D_ + d) * S_ + s0) = pk;
      }
  } else {
    // SWAPPED: row = n-off = quad*4+reg, col = m-off = l16. RoPE pair (d,d+32)=(j4,j4+2).
    u16* dst = (which == 0) ? Q : K;
#pragma unroll
    for (int i4 = 0; i4 < 4; ++i4)
#pragma unroll
      for (int j4 = 0; j4 < 2; ++j4) {
        int m = mbase + wm * 64 + i4 * 16 + l16;
        int n1 = nbase + wn * 64 + j4 * 16 + quad * 4;
        int b = m >> 11, s = m & 2047;
        int h = n1 >> 6, d1 = n1 & 63;  // d1 in [0,32), multiple of 4
        float4 c4 = *(const float4*)(cos_t + s * 32 + d1);
        float4 s4 = *(const float4*)(sin_t + s * 32 + d1);
        float y1[4], y2[4];
#pragma unroll
        for (int r = 0; r < 4; ++r) {
          float cr = ((const float*)&c4)[r], sr = ((const float*)&s4)[r];
          float x1 = acc[i4][j4][r], x2 = acc[i4][j4 + 2][r];
          y1[r] = x1 * cr - x2 * sr;
          y2[r] = x2 * cr + x1 * sr;
        }
        size_t base = ((size_t)(b * H_ + h) * S_ + s) * D_;
        uint2 p1, p2;
        p1.x = packbf2(y1[0], y1[1]);
        p1.y = packbf2(y1[2], y1[3]);
        p2.x = packbf2(y2[0], y2[1]);
        p2.y = packbf2(y2[2], y2[3]);
        *(uint2*)(dst + base + d1) = p1;
        *(uint2*)(dst + base + d1 + 32) = p2;
      }
  }
}

// ---------------- Flash attention: 128 q/block, 32 q/wave (2 groups) ----------------
// grid (16, 32). 4 waves. 64-key tiles, double-buffered K/V, 1 barrier/tile.
// S^T = K*Q^T -> C: row=key(quad*4+reg), col=q(l16). K/V LDS reads shared by 2 groups.
__global__ __launch_bounds__(256) void flash_kernel(
    const u16* __restrict__ Q, const u16* __restrict__ K, const u16* __restrict__ Vt,
    const float* __restrict__ mask, float* __restrict__ out) {
  __shared__ char smem[49152];
  // buf b: K @ b*16384, V @ b*16384+8192. P @ 32768 + wave*4096 (+ group*2048).
  int tid = threadIdx.x, lane = tid & 63, wave = tid >> 6;
  int quad = lane >> 4, l16 = lane & 15;
  int bh = blockIdx.y, b = bh >> 4, h = bh & 15;
  int qbase = blockIdx.x * 128;
  int qw = qbase + wave * 32;
  char* Pw = smem + 32768 + wave * 4096;
  const float* mrow = mask + b * S_;
  const u16* Kbase = K + (size_t)bh * S_ * D_;
  const u16* Vbase = Vt + (size_t)bh * D_ * S_;

  bf16x8 qfrag[2][2];
#pragma unroll
  for (int g = 0; g < 2; ++g) {
    const u16* qp = Q + ((size_t)bh * S_ + qw + g * 16 + l16) * D_ + quad * 8;
    qfrag[g][0] = *(const bf16x8*)qp;
    qfrag[g][1] = *(const bf16x8*)(qp + 32);
  }
  f32x4 o0[4] = {}, o1[4] = {};
  float l0 = 0.f, l1 = 0.f;

  // stage tile 0 into buffer 0
#pragma unroll
  for (int it = 0; it < 2; ++it) {
    int i = it * 256 + tid;
    int r = i >> 3, gs = i & 7, gsrc = gs ^ (r & 7);
    gl2lds16(Kbase + (size_t)r * D_ + gsrc * 8, smem + i * 16);
    gl2lds16(Vbase + (size_t)r * S_ + gsrc * 8, smem + 8192 + i * 16);
  }

  for (int kt = 0; kt < 32; ++kt) {
    int kbase = kt * 64;
    char* Ks = smem + (kt & 1) * 16384;
    char* Vs = Ks + 8192;
    __syncthreads();  // current buffer staged (vmcnt drain in barrier)

    if (kt < 31) {  // prefetch next tile
      char* Kn = smem + ((kt + 1) & 1) * 16384;
      char* Vn = Kn + 8192;
      int nb = kbase + 64;
#pragma unroll
      for (int it = 0; it < 2; ++it) {
        int i = it * 256 + tid;
        int r = i >> 3, gs = i & 7, gsrc = gs ^ (r & 7);
        gl2lds16(Kbase + (size_t)(nb + r) * D_ + gsrc * 8, Kn + i * 16);
        gl2lds16(Vbase + (size_t)r * S_ + nb + gsrc * 8, Vn + i * 16);
      }
    }

    float4 mv4[4];
#pragma unroll
    for (int jt = 0; jt < 4; ++jt)
      mv4[jt] = *(const float4*)(mrow + kbase + jt * 16 + quad * 4);

    // S^T for both q-groups, sharing each K fragment read
    f32x4 s0[4] = {}, s1[4] = {};
#pragma unroll
    for (int jt = 0; jt < 4; ++jt) {
      int r = jt * 16 + l16;
#pragma unroll
      for (int kh = 0; kh < 2; ++kh) {
        int L = r * 8 + ((kh * 4 + quad) ^ (r & 7));
        bf16x8 kf = *(const bf16x8*)(Ks + L * 16);
        s0[jt] = __builtin_amdgcn_mfma_f32_16x16x32_bf16(kf, qfrag[0][kh], s0[jt], 0, 0, 0);
        s1[jt] = __builtin_amdgcn_mfma_f32_16x16x32_bf16(kf, qfrag[1][kh], s1[jt], 0, 0, 0);
      }
    }

    // fixed-max softmax; bf16 truncation; l from truncated p; packed P writes
#pragma unroll
    for (int jt = 0; jt < 4; ++jt) {
      float mvs[4];
#pragma unroll
      for (int r = 0; r < 4; ++r)
        mvs[r] = fmaf(((const float*)&mv4[jt])[r], LOG2E, -MAXC_LOG2);
      uint32_t bt0[4], bt1[4];
#pragma unroll
      for (int r = 0; r < 4; ++r) {
        float p0 = __builtin_amdgcn_exp2f(fmaf(s0[jt][r], SCALE_LOG2, mvs[r]));
        float p1 = __builtin_amdgcn_exp2f(fmaf(s1[jt][r], SCALE_LOG2, mvs[r]));
        bt0[r] = __builtin_bit_cast(uint32_t, p0) & 0xffff0000u;
        bt1[r] = __builtin_bit_cast(uint32_t, p1) & 0xffff0000u;
        l0 += __builtin_bit_cast(float, bt0[r]);
        l1 += __builtin_bit_cast(float, bt1[r]);
      }
      int chunk = (jt * 4 + quad) ^ l16;
      uint2 pk0, pk1;
      pk0.x = (bt0[0] >> 16) | bt0[1];
      pk0.y = (bt0[2] >> 16) | bt0[3];
      pk1.x = (bt1[0] >> 16) | bt1[1];
      pk1.y = (bt1[2] >> 16) | bt1[3];
      *(uint2*)(Pw + l16 * 128 + chunk * 8) = pk0;
      *(uint2*)(Pw + 2048 + l16 * 128 + chunk * 8) = pk1;
    }

    // pfrag A-layout reads for both groups
    bf16x8 p0[2], p1[2];
#pragma unroll
    for (int kh = 0; kh < 2; ++kh) {
      int c0 = kh * 8 + quad * 2;
      union { uint2 u[2]; bf16x8 v; } cv0, cv1;
      cv0.u[0] = *(const uint2*)(Pw + l16 * 128 + ((c0) ^ l16) * 8);
      cv0.u[1] = *(const uint2*)(Pw + l16 * 128 + ((c0 + 1) ^ l16) * 8);
      cv1.u[0] = *(const uint2*)(Pw + 2048 + l16 * 128 + ((c0) ^ l16) * 8);
      cv1.u[1] = *(const uint2*)(Pw + 2048 + l16 * 128 + ((c0 + 1) ^ l16) * 8);
      p0[kh] = cv0.v;
      p1[kh] = cv1.v;
    }

    // O += P V, sharing each V fragment read
#pragma unroll
    for (int jd = 0; jd < 4; ++jd) {
      int r = jd * 16 + l16;
#pragma unroll
      for (int kh = 0; kh < 2; ++kh) {
        int L = r * 8 + ((kh * 4 + quad) ^ (r & 7));
        bf16x8 vf = *(const bf16x8*)(Vs + L * 16);
        o0[jd] = __builtin_amdgcn_mfma_f32_16x16x32_bf16(p0[kh], vf, o0[jd], 0, 0, 0);
        o1[jd] = __builtin_amdgcn_mfma_f32_16x16x32_bf16(p1[kh], vf, o1[jd], 0, 0, 0);
      }
    }
  }

  // epilogue per group: l reduction over quads, then divide + store
#pragma unroll
  for (int g = 0; g < 2; ++g) {
    float lsum = g ? l1 : l0;
    lsum += __shfl_xor(lsum, 16, 64);
    lsum += __shfl_xor(lsum, 32, 64);
    float inv_l[4];
#pragma unroll
    for (int r = 0; r < 4; ++r) inv_l[r] = 1.0f / __shfl(lsum, quad * 4 + r, 64);
    f32x4* o = g ? o1 : o0;
#pragma unroll
    for (int jd = 0; jd < 4; ++jd) {
#pragma unroll
      for (int r = 0; r < 4; ++r) {
        int q = qw + g * 16 + quad * 4 + r;
        int d = jd * 16 + l16;
        out[(((size_t)b * S_ + q) * H_ + h) * D_ + d] = o[jd][r] * inv_l[r];
      }
    }
  }
}

extern "C" void kernel_launch(void* const* d_in, const int* in_sizes, int n_in,
                              void* d_out, int out_size, void* d_ws, size_t ws_size,
                              hipStream_t stream) {
  const float* hid = (const float*)d_in[0];
  const float* mask = (const float*)d_in[1];
  const float* Wq = (const float*)d_in[2];
  const float* Wk = (const float*)d_in[3];
  const float* Wv = (const float*)d_in[4];
  float* out = (float*)d_out;
  char* ws = (char*)d_ws;

  u16* Xbf = (u16*)ws;                              // 8 MB
  u16* Wqb = (u16*)(ws + (8u << 20));               // 2 MB
  u16* Wkb = (u16*)(ws + (10u << 20));              // 2 MB
  u16* Wvb = (u16*)(ws + (12u << 20));              // 2 MB
  u16* Qb = (u16*)(ws + (14u << 20));               // 8 MB (BH,S,D)
  u16* Kb = (u16*)(ws + (22u << 20));               // 8 MB (BH,S,D)
  u16* Vtb = (u16*)(ws + (30u << 20));              // 8 MB (BH,D,S)
  float* cos_t = (float*)(ws + (38u << 20));        // 256 KB
  float* sin_t = (float*)(ws + (38u << 20) + (256u << 10));

  // 1048576 + 786432 + 65536 = 1900544 threads = 7424 blocks of 256
  prep_kernel<<<7424, 256, 0, stream>>>(hid, Wq, Wk, Wv, Xbf, Wqb, Wkb, Wvb, cos_t, sin_t);
  qkv_gemm_kernel<<<dim3(24, 32), 256, 0, stream>>>(Xbf, Wqb, Wkb, Wvb, cos_t, sin_t,
                                                    Qb, Kb, Vtb);
  flash_kernel<<<dim3(16, 32), 256, 0, stream>>>(Qb, Kb, Vtb, mask, out);
}